// Round 6
// baseline (890.037 us; speedup 1.0000x reference)
//
#include <hip/hip_runtime.h>
#include <stdint.h>

// GraphConvLayer: out[n,:] = W[type[n]] @ (A @ x)[n,:]
// N=16384, D=128, T=8.  A is 1 GiB f32 read exactly once -> HBM floor ~163us.
// Round 6: zero-LDS, zero-barrier main loop (R5 structure) with BUILTIN MFMA.
// R5's NaN: inline-asm MFMA fed by hot VALU results (cvt) + vDst read right
// after -- CDNA wait-state hazards invisible to the hazard recognizer through
// opaque asm. Builtin MFMA makes the compiler insert the required s_nops and
// handle scheduling; A conversion via (__bf16) casts -> v_cvt_pk_bf16_f32.

#define N_NODES 16384
#define DIM     128
#define NTYPES  8
#define BM      64
#define BK      64
#define NIT     (N_NODES / BK)   // 256

typedef float  f32x4  __attribute__((ext_vector_type(4)));
typedef __bf16 bf16x8 __attribute__((ext_vector_type(8)));

__device__ __attribute__((aligned(16))) unsigned short g_xT[DIM * N_NODES];      // [d][n], 4 MiB
__device__ __attribute__((aligned(16))) unsigned short g_Wb[NTYPES * DIM * DIM]; // [t][o][d], 256 KiB

__device__ __forceinline__ unsigned int f2b(float f) {
    unsigned int u = __float_as_uint(f);
    u += 0x7FFFu + ((u >> 16) & 1u);   // round-to-nearest-even
    return u >> 16;
}
#define BF_LO(u) __uint_as_float((unsigned int)(u) << 16)
#define BF_HI(u) __uint_as_float((unsigned int)(u) & 0xFFFF0000u)

__device__ __forceinline__ bf16x8 cvt8(const float4 lo, const float4 hi) {
    bf16x8 r;
    r[0] = (__bf16)lo.x; r[1] = (__bf16)lo.y; r[2] = (__bf16)lo.z; r[3] = (__bf16)lo.w;
    r[4] = (__bf16)hi.x; r[5] = (__bf16)hi.y; r[6] = (__bf16)hi.z; r[7] = (__bf16)hi.w;
    return r;
}

// ---------------- fused prep kernel ----------------
// blocks 0..63: xT transpose+convert; blocks 64..95: W convert.

__global__ void prep_all(const float* __restrict__ x, const float* __restrict__ w) {
    const int tid = threadIdx.x;
    if (blockIdx.x < 64) {
        int n = blockIdx.x * 256 + tid;
        const float* row = x + (size_t)n * DIM;
#pragma unroll
        for (int d0 = 0; d0 < DIM; d0 += 4) {
            float4 v = *(const float4*)(row + d0);
            g_xT[(d0 + 0) * N_NODES + n] = (unsigned short)f2b(v.x);
            g_xT[(d0 + 1) * N_NODES + n] = (unsigned short)f2b(v.y);
            g_xT[(d0 + 2) * N_NODES + n] = (unsigned short)f2b(v.z);
            g_xT[(d0 + 3) * N_NODES + n] = (unsigned short)f2b(v.w);
        }
    } else {
        int base = ((blockIdx.x - 64) * 256 + tid) * 16;
#pragma unroll
        for (int j = 0; j < 4; ++j) {
            float4 v = *(const float4*)(w + base + j * 4);
            ushort4 o;
            o.x = (unsigned short)f2b(v.x); o.y = (unsigned short)f2b(v.y);
            o.z = (unsigned short)f2b(v.z); o.w = (unsigned short)f2b(v.w);
            *(ushort4*)(g_Wb + base + j * 4) = o;
        }
    }
}

// ---------------- main fused kernel ----------------

#define BCOL ((size_t)16 * N_NODES)   // 16 xT rows (one n-tile) in shorts

// load tile t into one parity's named regs: A = 4x float4 (k and k+32 pairs),
// B = 8x bf16x8 (kc*4+nt). All full-line coalesced (16 rows x 128B / x 64B).
#define LOADT(t, A0, A1, A2, A3, B0, B1, B2, B3, B4, B5, B6, B7) do {          \
    A0 = *(const float4*)(aPtr + (size_t)(t) * BK);                            \
    A1 = *(const float4*)(aPtr + (size_t)(t) * BK + 4);                        \
    A2 = *(const float4*)(aPtr + (size_t)(t) * BK + 32);                       \
    A3 = *(const float4*)(aPtr + (size_t)(t) * BK + 36);                       \
    B0 = *(const bf16x8*)(bPtr + (size_t)(t) * BK);                            \
    B1 = *(const bf16x8*)(bPtr + 1 * BCOL + (size_t)(t) * BK);                 \
    B2 = *(const bf16x8*)(bPtr + 2 * BCOL + (size_t)(t) * BK);                 \
    B3 = *(const bf16x8*)(bPtr + 3 * BCOL + (size_t)(t) * BK);                 \
    B4 = *(const bf16x8*)(bPtr + (size_t)(t) * BK + 32);                       \
    B5 = *(const bf16x8*)(bPtr + 1 * BCOL + (size_t)(t) * BK + 32);            \
    B6 = *(const bf16x8*)(bPtr + 2 * BCOL + (size_t)(t) * BK + 32);            \
    B7 = *(const bf16x8*)(bPtr + 3 * BCOL + (size_t)(t) * BK + 32);            \
} while (0)

// convert A in-register and run 8 MFMAs for one tile (builtin: hazards handled)
#define COMPUTE(A0, A1, A2, A3, B0, B1, B2, B3, B4, B5, B6, B7) do {           \
    bf16x8 ak0 = cvt8(A0, A1);                                                 \
    bf16x8 ak1 = cvt8(A2, A3);                                                 \
    acc0 = __builtin_amdgcn_mfma_f32_16x16x32_bf16(ak0, B0, acc0, 0, 0, 0);    \
    acc1 = __builtin_amdgcn_mfma_f32_16x16x32_bf16(ak0, B1, acc1, 0, 0, 0);    \
    acc2 = __builtin_amdgcn_mfma_f32_16x16x32_bf16(ak0, B2, acc2, 0, 0, 0);    \
    acc3 = __builtin_amdgcn_mfma_f32_16x16x32_bf16(ak0, B3, acc3, 0, 0, 0);    \
    acc0 = __builtin_amdgcn_mfma_f32_16x16x32_bf16(ak1, B4, acc0, 0, 0, 0);    \
    acc1 = __builtin_amdgcn_mfma_f32_16x16x32_bf16(ak1, B5, acc1, 0, 0, 0);    \
    acc2 = __builtin_amdgcn_mfma_f32_16x16x32_bf16(ak1, B6, acc2, 0, 0, 0);    \
    acc3 = __builtin_amdgcn_mfma_f32_16x16x32_bf16(ak1, B7, acc3, 0, 0, 0);    \
} while (0)

__global__ __launch_bounds__(512, 2) void gconv_main(
    const float* __restrict__ adj,
    const int* __restrict__ types,
    float* __restrict__ out)
{
    __shared__ __align__(16) float agg[BM * 132];   // epilogue only (33792 B)

    const int tid  = threadIdx.x;
    const int w    = tid >> 6;          // 0..7
    const int lane = tid & 63;
    const int m0   = blockIdx.x * BM;

    const int mrow = (w & 3) * 16;      // wave's 16 output rows (of 64)
    const int ncol = (w >> 2) * 64;     // wave's 64 output cols (of 128)

    f32x4 acc0 = {}, acc1 = {}, acc2 = {}, acc3 = {};

    // per-lane fragment base pointers
    const float* aPtr = adj + (size_t)(m0 + mrow + (lane & 15)) * N_NODES + ((lane >> 4) << 3);
    const unsigned short* bPtr = g_xT + (size_t)(ncol + (lane & 15)) * N_NODES + ((lane >> 4) << 3);

    // two parities of named registers (no arrays -> no scratch, rule #20)
    float4 pA0, pA1, pA2, pA3, qA0, qA1, qA2, qA3;
    bf16x8 pB0, pB1, pB2, pB3, pB4, pB5, pB6, pB7;
    bf16x8 qB0, qB1, qB2, qB3, qB4, qB5, qB6, qB7;

    LOADT(0, pA0, pA1, pA2, pA3, pB0, pB1, pB2, pB3, pB4, pB5, pB6, pB7);

    // 2 tiles per iteration; next tile's loads issue before current compute,
    // so every tile has >= one compute-phase of latency cover. No barriers.
    for (int i = 0; i < 127; ++i) {
        const int t = 2 * i;
        LOADT(t + 1, qA0, qA1, qA2, qA3, qB0, qB1, qB2, qB3, qB4, qB5, qB6, qB7);
        COMPUTE(pA0, pA1, pA2, pA3, pB0, pB1, pB2, pB3, pB4, pB5, pB6, pB7);
        LOADT(t + 2, pA0, pA1, pA2, pA3, pB0, pB1, pB2, pB3, pB4, pB5, pB6, pB7);
        COMPUTE(qA0, qA1, qA2, qA3, qB0, qB1, qB2, qB3, qB4, qB5, qB6, qB7);
    }
    LOADT(255, qA0, qA1, qA2, qA3, qB0, qB1, qB2, qB3, qB4, qB5, qB6, qB7);
    COMPUTE(pA0, pA1, pA2, pA3, pB0, pB1, pB2, pB3, pB4, pB5, pB6, pB7);
    COMPUTE(qA0, qA1, qA2, qA3, qB0, qB1, qB2, qB3, qB4, qB5, qB6, qB7);

    // ---- epilogue: acc -> LDS agg (f32), then per-row W[type] dots ----
#pragma unroll
    for (int r = 0; r < 4; ++r) {
        const int gr = (mrow + (lane >> 4) * 4 + r) * 132 + ncol + (lane & 15);
        agg[gr +  0] = acc0[r];
        agg[gr + 16] = acc1[r];
        agg[gr + 32] = acc2[r];
        agg[gr + 48] = acc3[r];
    }
    __syncthreads();

    const int rbase = w * 8;   // 8 rows per wave
    for (int rr = 0; rr < 8; ++rr) {
        const int rw = rbase + rr;
        const int nn = m0 + rw;
        const int ty = types[nn];                      // wave-uniform
        const unsigned short* Wt = g_Wb + ty * (DIM * DIM);
        const int o0 = lane * 2;
        const float* aggRow = agg + rw * 132;
        float s0 = 0.f, s1 = 0.f;
#pragma unroll
        for (int d0 = 0; d0 < DIM; d0 += 8) {
            float4 ga = *(const float4*)(aggRow + d0);
            float4 gb = *(const float4*)(aggRow + d0 + 4);
            uint4 wa = *(const uint4*)(Wt + o0 * DIM + d0);
            uint4 wb = *(const uint4*)(Wt + (o0 + 1) * DIM + d0);
            s0 += ga.x * BF_LO(wa.x) + ga.y * BF_HI(wa.x) + ga.z * BF_LO(wa.y) + ga.w * BF_HI(wa.y);
            s0 += gb.x * BF_LO(wa.z) + gb.y * BF_HI(wa.z) + gb.z * BF_LO(wa.w) + gb.w * BF_HI(wa.w);
            s1 += ga.x * BF_LO(wb.x) + ga.y * BF_HI(wb.x) + ga.z * BF_LO(wb.y) + ga.w * BF_HI(wb.y);
            s1 += gb.x * BF_LO(wb.z) + gb.y * BF_HI(wb.z) + gb.z * BF_LO(wb.w) + gb.w * BF_HI(wb.w);
        }
        float2 res; res.x = s0; res.y = s1;
        *(float2*)(out + (size_t)nn * DIM + o0) = res;
    }
}

// ---------------- launch ----------------

extern "C" void kernel_launch(void* const* d_in, const int* in_sizes, int n_in,
                              void* d_out, int out_size, void* d_ws, size_t ws_size,
                              hipStream_t stream) {
    const float* x     = (const float*)d_in[0];
    const int*   types = (const int*)d_in[1];
    const float* adj   = (const float*)d_in[2];
    const float* wt    = (const float*)d_in[3];
    float* out = (float*)d_out;

    hipLaunchKernelGGL(prep_all, dim3(96), dim3(256), 0, stream, x, wt);
    hipLaunchKernelGGL(gconv_main, dim3(N_NODES / BM), dim3(512), 0, stream, adj, types, out);
}

// Round 7
// 776.161 us; speedup vs baseline: 1.1467x; 1.1467x over previous
//
#include <hip/hip_runtime.h>
#include <stdint.h>

// GraphConvLayer: out[n,:] = W[type[n]] @ (A @ x)[n,:]
// N=16384, D=128, T=8.  A is 1 GiB f32 read exactly once -> HBM floor ~163us.
// Round 7: split-K occupancy fix. R3's pinned-barrier pipeline ran at 1
// block/CU -> every barrier convoy was dead CU time (2x floor). R6 showed
// (FETCH=1.05GB, VGPR=76, VALUBusy 5%) that unpinned loads get rescheduled
// to uses -> no MLP. So: keep barriers (they pin the schedule), get overlap
// from TLP instead: SPLITK=4, grid=1024 -> 4 independent 256-thread blocks
// per CU at unsynchronized barrier phases. LDS = A dbuf only (18KB); B read
// directly from per-XCD-L2-resident g_xT; partials in f32 device buffer,
// reduced + W-projected by a small epilogue kernel (W stays f32).

#define N_NODES 16384
#define DIM     128
#define NTYPES  8
#define BM      64
#define BK      64
#define SPLITK  4
#define KSLICE  (N_NODES / SPLITK)   // 4096
#define NTILES  (KSLICE / BK)        // 64

typedef float  f32x4  __attribute__((ext_vector_type(4)));
typedef __bf16 bf16x8 __attribute__((ext_vector_type(8)));

__device__ __attribute__((aligned(16))) unsigned short g_xT[DIM * N_NODES];        // [d][n], 4 MiB bf16
__device__ __attribute__((aligned(16))) float g_part[SPLITK * N_NODES * DIM];      // 32 MiB f32 partials

__device__ __forceinline__ unsigned int f2b(float f) {
    unsigned int u = __float_as_uint(f);
    u += 0x7FFFu + ((u >> 16) & 1u);   // round-to-nearest-even
    return u >> 16;
}

__device__ __forceinline__ bf16x8 cvt8(const float4 lo, const float4 hi) {
    bf16x8 r;
    r[0] = (__bf16)lo.x; r[1] = (__bf16)lo.y; r[2] = (__bf16)lo.z; r[3] = (__bf16)lo.w;
    r[4] = (__bf16)hi.x; r[5] = (__bf16)hi.y; r[6] = (__bf16)hi.z; r[7] = (__bf16)hi.w;
    return r;
}

// ---------------- prep: x -> bf16 transposed [d][n] ----------------

__global__ void prep_xT(const float* __restrict__ x) {
    int n = blockIdx.x * 256 + threadIdx.x;          // 64 blocks x 256
    const float* row = x + (size_t)n * DIM;
#pragma unroll
    for (int d0 = 0; d0 < DIM; d0 += 4) {
        float4 v = *(const float4*)(row + d0);
        g_xT[(d0 + 0) * N_NODES + n] = (unsigned short)f2b(v.x);
        g_xT[(d0 + 1) * N_NODES + n] = (unsigned short)f2b(v.y);
        g_xT[(d0 + 2) * N_NODES + n] = (unsigned short)f2b(v.z);
        g_xT[(d0 + 3) * N_NODES + n] = (unsigned short)f2b(v.w);
    }
}

// ---------------- main GEMM kernel (split-K) ----------------

#define ASTRIDE 72                           // 64 + 8 pad shorts (144 B rows)
#define BCOL ((size_t)16 * N_NODES)          // one 16-col n-tile stride in g_xT shorts

// LDS-visibility-only barrier: VMEM prefetch stays in flight across it
#define BAR() asm volatile("s_waitcnt lgkmcnt(0)\n\ts_barrier" ::: "memory")

#define LOADA(t, A0, A1, A2, A3) do {                    \
    A0 = *(const float4*)(aPtr + (size_t)(t) * BK);      \
    A1 = *(const float4*)(aPtr + (size_t)(t) * BK + 4);  \
    A2 = *(const float4*)(aPtr + (size_t)(t) * BK + 8);  \
    A3 = *(const float4*)(aPtr + (size_t)(t) * BK + 12); \
} while (0)

#define STOREA(As_, A0, A1, A2, A3) do {                    \
    *(bf16x8*)((As_) + ar * ASTRIDE + akq)     = cvt8(A0, A1); \
    *(bf16x8*)((As_) + ar * ASTRIDE + akq + 8) = cvt8(A2, A3); \
} while (0)

#define MF(nt) do {                                                                                  \
    acc##nt = __builtin_amdgcn_mfma_f32_16x16x32_bf16(a0_, *(const bf16x8*)(bt_ + (size_t)(nt) * BCOL),      acc##nt, 0, 0, 0); \
    acc##nt = __builtin_amdgcn_mfma_f32_16x16x32_bf16(a1_, *(const bf16x8*)(bt_ + (size_t)(nt) * BCOL + 32), acc##nt, 0, 0, 0); \
} while (0)

#define COMPUTE(As_, t) do {                                                          \
    const unsigned short* bt_ = bPtr + (size_t)(t) * BK;                              \
    bf16x8 a0_ = *(const bf16x8*)((As_) + (mrow + (lane & 15)) * ASTRIDE + kk);       \
    bf16x8 a1_ = *(const bf16x8*)((As_) + (mrow + (lane & 15)) * ASTRIDE + kk + 32);  \
    MF(0); MF(1); MF(2); MF(3); MF(4); MF(5); MF(6); MF(7);                           \
} while (0)

__global__ __launch_bounds__(256, 4) void gconv_main(const float* __restrict__ adj)
{
    __shared__ __align__(16) unsigned short Alds[2 * BM * ASTRIDE];   // 18432 B
    unsigned short* As0 = Alds;
    unsigned short* As1 = Alds + BM * ASTRIDE;

    const int tid  = threadIdx.x;
    const int w    = tid >> 6;                 // 0..3
    const int lane = tid & 63;
    const int ks   = blockIdx.x & (SPLITK - 1);          // k-slice
    const int m0   = (blockIdx.x >> 2) * BM;             // row block
    const int kb   = ks * KSLICE;

    const int mrow = w * 16;                   // wave's 16 output rows; all 128 cols
    const int kk   = (lane >> 4) * 8;

    f32x4 acc0 = {}, acc1 = {}, acc2 = {}, acc3 = {},
          acc4 = {}, acc5 = {}, acc6 = {}, acc7 = {};

    // A staging: thread -> row ar (0..63), k-quarter akq (16 floats)
    const int ar  = tid >> 2;
    const int akq = (tid & 3) * 16;
    const float* aPtr = adj + (size_t)(m0 + ar) * N_NODES + kb + akq;

    // B fragments straight from g_xT (per-XCD L2-resident slice)
    const unsigned short* bPtr = g_xT + (size_t)(lane & 15) * N_NODES + kb + kk;

    float4 p0, p1, p2, p3, q0, q1, q2, q3;     // 2-deep named-reg A pipeline

    LOADA(0, p0, p1, p2, p3);
    LOADA(1, q0, q1, q2, q3);
    STOREA(As0, p0, p1, p2, p3);
    BAR();

    for (int i = 0; i < NTILES / 2 - 1; ++i) {       // 31 iterations, tiles 0..61
        const int t0 = 2 * i;
        LOADA(t0 + 2, p0, p1, p2, p3);
        COMPUTE(As0, t0);
        STOREA(As1, q0, q1, q2, q3);
        BAR();
        LOADA(t0 + 3, q0, q1, q2, q3);
        COMPUTE(As1, t0 + 1);
        STOREA(As0, p0, p1, p2, p3);
        BAR();
    }
    COMPUTE(As0, NTILES - 2);
    STOREA(As1, q0, q1, q2, q3);
    BAR();
    COMPUTE(As1, NTILES - 1);

    // partial store: col = lane&15 (in n-tile), row = mrow + (lane>>4)*4 + r
    float* pp = g_part + (size_t)ks * N_NODES * DIM
              + (size_t)(m0 + mrow + (lane >> 4) * 4) * DIM + (lane & 15);
#define STACC(nt) do {                          \
    pp[0 * DIM + (nt) * 16] = acc##nt[0];       \
    pp[1 * DIM + (nt) * 16] = acc##nt[1];       \
    pp[2 * DIM + (nt) * 16] = acc##nt[2];       \
    pp[3 * DIM + (nt) * 16] = acc##nt[3];       \
} while (0)
    STACC(0); STACC(1); STACC(2); STACC(3);
    STACC(4); STACC(5); STACC(6); STACC(7);
#undef STACC
}

// ---------------- epilogue: reduce partials + W[type] projection (f32) ----------------

#define BF_LO(u) __uint_as_float((unsigned int)(u) << 16)
#define BF_HI(u) __uint_as_float((unsigned int)(u) & 0xFFFF0000u)

__global__ __launch_bounds__(256) void gconv_epi(
    const float* __restrict__ wt,
    const int* __restrict__ types,
    float* __restrict__ out)
{
    __shared__ __align__(16) float agg[BM * 132];   // 33792 B

    const int tid  = threadIdx.x;
    const int w    = tid >> 6;
    const int lane = tid & 63;
    const int m0   = blockIdx.x * BM;

    // phase 1: agg[node][d] = sum_s part[s][m0+node][d]
#pragma unroll
    for (int j = 0; j < 8; ++j) {
        const int f    = tid + j * 256;        // float4 index within 64x128 tile
        const int node = f >> 5;
        const int d4   = (f & 31) * 4;
        const float* p = g_part + (size_t)(m0 + node) * DIM + d4;
        float4 s0 = *(const float4*)(p + 0 * (size_t)N_NODES * DIM);
        float4 s1 = *(const float4*)(p + 1 * (size_t)N_NODES * DIM);
        float4 s2 = *(const float4*)(p + 2 * (size_t)N_NODES * DIM);
        float4 s3 = *(const float4*)(p + 3 * (size_t)N_NODES * DIM);
        float4 s; s.x = s0.x + s1.x + s2.x + s3.x; s.y = s0.y + s1.y + s2.y + s3.y;
        s.z = s0.z + s1.z + s2.z + s3.z; s.w = s0.w + s1.w + s2.w + s3.w;
        *(float4*)&agg[node * 132 + d4] = s;
    }
    __syncthreads();

    // phase 2: out[n] = W[type[n]] @ agg[n]  (f32, lane -> 2 output features)
    const int rbase = w * 16;   // 16 nodes per wave
    for (int rr = 0; rr < 16; ++rr) {
        const int rw = rbase + rr;
        const int nn = m0 + rw;
        const int ty = types[nn];                       // wave-uniform
        const float* Wt = wt + (size_t)ty * DIM * DIM;
        const int o0 = lane * 2;
        const float* aggRow = agg + rw * 132;
        float s0 = 0.f, s1 = 0.f;
#pragma unroll
        for (int d0 = 0; d0 < DIM; d0 += 8) {
            float4 ga = *(const float4*)(aggRow + d0);
            float4 gb = *(const float4*)(aggRow + d0 + 4);
            float4 wa0 = *(const float4*)(Wt + (size_t)o0 * DIM + d0);
            float4 wa1 = *(const float4*)(Wt + (size_t)o0 * DIM + d0 + 4);
            float4 wb0 = *(const float4*)(Wt + (size_t)(o0 + 1) * DIM + d0);
            float4 wb1 = *(const float4*)(Wt + (size_t)(o0 + 1) * DIM + d0 + 4);
            s0 += ga.x * wa0.x + ga.y * wa0.y + ga.z * wa0.z + ga.w * wa0.w;
            s0 += gb.x * wa1.x + gb.y * wa1.y + gb.z * wa1.z + gb.w * wa1.w;
            s1 += ga.x * wb0.x + ga.y * wb0.y + ga.z * wb0.z + ga.w * wb0.w;
            s1 += gb.x * wb1.x + gb.y * wb1.y + gb.z * wb1.z + gb.w * wb1.w;
        }
        float2 res; res.x = s0; res.y = s1;
        *(float2*)(out + (size_t)nn * DIM + o0) = res;
    }
}

// ---------------- launch ----------------

extern "C" void kernel_launch(void* const* d_in, const int* in_sizes, int n_in,
                              void* d_out, int out_size, void* d_ws, size_t ws_size,
                              hipStream_t stream) {
    const float* x     = (const float*)d_in[0];
    const int*   types = (const int*)d_in[1];
    const float* adj   = (const float*)d_in[2];
    const float* wt    = (const float*)d_in[3];
    float* out = (float*)d_out;

    hipLaunchKernelGGL(prep_xT, dim3(64), dim3(256), 0, stream, x);
    hipLaunchKernelGGL(gconv_main, dim3((N_NODES / BM) * SPLITK), dim3(256), 0, stream, adj);
    hipLaunchKernelGGL(gconv_epi, dim3(N_NODES / BM), dim3(256), 0, stream, wt, types, out);
}

// Round 8
// 682.200 us; speedup vs baseline: 1.3047x; 1.1377x over previous
//
#include <hip/hip_runtime.h>
#include <stdint.h>

// GraphConvLayer: out[n,:] = W[type[n]] @ (A @ x)[n,:]
// N=16384, D=128, T=8.  A is 1 GiB f32 read exactly once -> HBM floor ~163us.
// Round 8 = Round 3 (best, 366us) minus X-LDS-staging:
//   - A: 4-deep named-register prefetch -> f32->bf16 cvt -> double-buffered LDS
//   - B: 2-deep named-register prefetch straight from L2-resident g_xT
//     (plain loads pinned between BAR "memory" clobbers, like R3's A loads)
//   - lgkm-only barriers: VMEM stays in flight across s_barrier
// Per-iter LDS traffic drops 104KB -> 24KB; X ds_writes leave the
// barrier-bounded critical path.

#define N_NODES 16384
#define DIM     128
#define NTYPES  8
#define BM      64
#define BK      64
#define NIT     (N_NODES / BK)   // 256

typedef float  f32x4  __attribute__((ext_vector_type(4)));
typedef __bf16 bf16x4 __attribute__((ext_vector_type(4)));
typedef __bf16 bf16x8 __attribute__((ext_vector_type(8)));

__device__ __attribute__((aligned(16))) unsigned short g_xT[DIM * N_NODES];      // [d][n], 4 MiB
__device__ __attribute__((aligned(16))) unsigned short g_Wb[NTYPES * DIM * DIM]; // [t][o][d], 256 KiB

__device__ __forceinline__ unsigned int f2b(float f) {
    unsigned int u = __float_as_uint(f);
    u += 0x7FFFu + ((u >> 16) & 1u);   // round-to-nearest-even
    return u >> 16;
}
#define BF_LO(u) __uint_as_float((unsigned int)(u) << 16)
#define BF_HI(u) __uint_as_float((unsigned int)(u) & 0xFFFF0000u)

__device__ __forceinline__ bf16x4 cvt4(const float4 v) {
    bf16x4 r;
    r[0] = (__bf16)v.x; r[1] = (__bf16)v.y; r[2] = (__bf16)v.z; r[3] = (__bf16)v.w;
    return r;
}

// ---------------- fused prep kernel ----------------
// blocks 0..63: xT transpose+convert; blocks 64..95: W convert.

__global__ void prep_all(const float* __restrict__ x, const float* __restrict__ w) {
    const int tid = threadIdx.x;
    if (blockIdx.x < 64) {
        int n = blockIdx.x * 256 + tid;
        const float* row = x + (size_t)n * DIM;
#pragma unroll
        for (int d0 = 0; d0 < DIM; d0 += 4) {
            float4 v = *(const float4*)(row + d0);
            g_xT[(d0 + 0) * N_NODES + n] = (unsigned short)f2b(v.x);
            g_xT[(d0 + 1) * N_NODES + n] = (unsigned short)f2b(v.y);
            g_xT[(d0 + 2) * N_NODES + n] = (unsigned short)f2b(v.z);
            g_xT[(d0 + 3) * N_NODES + n] = (unsigned short)f2b(v.w);
        }
    } else {
        int base = ((blockIdx.x - 64) * 256 + tid) * 16;
#pragma unroll
        for (int j = 0; j < 4; ++j) {
            float4 v = *(const float4*)(w + base + j * 4);
            ushort4 o;
            o.x = (unsigned short)f2b(v.x); o.y = (unsigned short)f2b(v.y);
            o.z = (unsigned short)f2b(v.z); o.w = (unsigned short)f2b(v.w);
            *(ushort4*)(g_Wb + base + j * 4) = o;
        }
    }
}

// ---------------- main fused kernel ----------------

#define ASTRIDE 72                           // 64 + 8 pad shorts (144 B rows)

// barrier with LDS-visibility only: VMEM prefetch stays in flight
#define BAR() asm volatile("s_waitcnt lgkmcnt(0)\n\ts_barrier" ::: "memory")

#define LOADA(t, Aa, Ab) do {                            \
    Aa = *(const float4*)(aPtr0 + (size_t)(t) * BK);     \
    Ab = *(const float4*)(aPtr1 + (size_t)(t) * BK);     \
} while (0)

#define LOADB(t, B0, B1, B2, B3, B4, B5, B6, B7) do {            \
    B0 = *(const bf16x8*)(bp0 + (size_t)(t) * BK);               \
    B1 = *(const bf16x8*)(bp1 + (size_t)(t) * BK);               \
    B2 = *(const bf16x8*)(bp2 + (size_t)(t) * BK);               \
    B3 = *(const bf16x8*)(bp3 + (size_t)(t) * BK);               \
    B4 = *(const bf16x8*)(bp0 + (size_t)(t) * BK + 32);          \
    B5 = *(const bf16x8*)(bp1 + (size_t)(t) * BK + 32);          \
    B6 = *(const bf16x8*)(bp2 + (size_t)(t) * BK + 32);          \
    B7 = *(const bf16x8*)(bp3 + (size_t)(t) * BK + 32);          \
} while (0)

#define STOREA(As_, Aa, Ab) do {                                 \
    *(bf16x4*)((As_) + ar0 * ASTRIDE + ak)        = cvt4(Aa);    \
    *(bf16x4*)((As_) + (ar0 + 32) * ASTRIDE + ak) = cvt4(Ab);    \
} while (0)

#define COMPUTE(As_, B0, B1, B2, B3, B4, B5, B6, B7) do {                             \
    bf16x8 a0_ = *(const bf16x8*)((As_) + (mrow + (lane & 15)) * ASTRIDE + kk);       \
    bf16x8 a1_ = *(const bf16x8*)((As_) + (mrow + (lane & 15)) * ASTRIDE + kk + 32);  \
    acc0 = __builtin_amdgcn_mfma_f32_16x16x32_bf16(a0_, B0, acc0, 0, 0, 0);           \
    acc1 = __builtin_amdgcn_mfma_f32_16x16x32_bf16(a0_, B1, acc1, 0, 0, 0);           \
    acc2 = __builtin_amdgcn_mfma_f32_16x16x32_bf16(a0_, B2, acc2, 0, 0, 0);           \
    acc3 = __builtin_amdgcn_mfma_f32_16x16x32_bf16(a0_, B3, acc3, 0, 0, 0);           \
    acc0 = __builtin_amdgcn_mfma_f32_16x16x32_bf16(a1_, B4, acc0, 0, 0, 0);           \
    acc1 = __builtin_amdgcn_mfma_f32_16x16x32_bf16(a1_, B5, acc1, 0, 0, 0);           \
    acc2 = __builtin_amdgcn_mfma_f32_16x16x32_bf16(a1_, B6, acc2, 0, 0, 0);           \
    acc3 = __builtin_amdgcn_mfma_f32_16x16x32_bf16(a1_, B7, acc3, 0, 0, 0);           \
} while (0)

__global__ __launch_bounds__(512, 2) void gconv_main(
    const float* __restrict__ adj,
    const int* __restrict__ types,
    float* __restrict__ out)
{
    __shared__ __align__(16) unsigned char lds[BM * 132 * 4];   // 33792 B (A dbuf 18432; agg reuse)
    unsigned short* As0 = (unsigned short*)lds;
    unsigned short* As1 = As0 + BM * ASTRIDE;

    const int tid  = threadIdx.x;
    const int w    = tid >> 6;          // 0..7
    const int lane = tid & 63;
    const int m0   = blockIdx.x * BM;

    const int mrow = (w & 3) * 16;      // wave's 16 output rows (of 64)
    const int ncol = (w >> 2) * 64;     // wave's 64 output cols (of 128)
    const int kk   = (lane >> 4) * 8;

    f32x4 acc0 = {}, acc1 = {}, acc2 = {}, acc3 = {};

    // A staging index math (512 threads load 64 rows x 64 f32 per tile)
    const int ar0 = tid >> 4;                 // rows 0..31 (+32)
    const int ak  = (tid & 15) * 4;           // 4-elem chunk in row
    const float* aBase = adj + (size_t)m0 * N_NODES;
    const float* aPtr0 = aBase + (size_t)ar0 * N_NODES + ak;
    const float* aPtr1 = aBase + (size_t)(ar0 + 32) * N_NODES + ak;

    // B fragment pointers (per nt-tile); 4 lanes share each 64B line -> coalesced
    const unsigned short* bp0 = g_xT + (size_t)(ncol +  0 + (lane & 15)) * N_NODES + kk;
    const unsigned short* bp1 = g_xT + (size_t)(ncol + 16 + (lane & 15)) * N_NODES + kk;
    const unsigned short* bp2 = g_xT + (size_t)(ncol + 32 + (lane & 15)) * N_NODES + kk;
    const unsigned short* bp3 = g_xT + (size_t)(ncol + 48 + (lane & 15)) * N_NODES + kk;

    // named register pipeline state (no arrays -> no scratch, rule #20)
    float4 a0a, a0b, a1a, a1b, a2a, a2b, a3a, a3b;            // A 4-deep
    bf16x8 bE0, bE1, bE2, bE3, bE4, bE5, bE6, bE7;            // B even parity
    bf16x8 bO0, bO1, bO2, bO3, bO4, bO5, bO6, bO7;            // B odd parity

    // ---- prologue ----
    LOADA(0, a0a, a0b);
    LOADA(1, a1a, a1b);
    LOADA(2, a2a, a2b);
    LOADA(3, a3a, a3b);
    LOADB(0, bE0, bE1, bE2, bE3, bE4, bE5, bE6, bE7);
    LOADB(1, bO0, bO1, bO2, bO3, bO4, bO5, bO6, bO7);
    STOREA(As0, a0a, a0b);
    BAR();

    // ---- steady state: 4 phases/iter. A(t) stored 3 phases after load;
    // B(t) consumed 2 phases after load. i = 0..62 computes tiles 0..251. ----
    for (int i = 0; i < 63; ++i) {
        const int t0 = 4 * i;
        LOADA(t0 + 4, a0a, a0b);
        COMPUTE(As0, bE0, bE1, bE2, bE3, bE4, bE5, bE6, bE7);
        LOADB(t0 + 2, bE0, bE1, bE2, bE3, bE4, bE5, bE6, bE7);
        STOREA(As1, a1a, a1b);
        BAR();
        LOADA(t0 + 5, a1a, a1b);
        COMPUTE(As1, bO0, bO1, bO2, bO3, bO4, bO5, bO6, bO7);
        LOADB(t0 + 3, bO0, bO1, bO2, bO3, bO4, bO5, bO6, bO7);
        STOREA(As0, a2a, a2b);
        BAR();
        LOADA(t0 + 6, a2a, a2b);
        COMPUTE(As0, bE0, bE1, bE2, bE3, bE4, bE5, bE6, bE7);
        LOADB(t0 + 4, bE0, bE1, bE2, bE3, bE4, bE5, bE6, bE7);
        STOREA(As1, a3a, a3b);
        BAR();
        LOADA(t0 + 7, a3a, a3b);
        COMPUTE(As1, bO0, bO1, bO2, bO3, bO4, bO5, bO6, bO7);
        LOADB(t0 + 5, bO0, bO1, bO2, bO3, bO4, bO5, bO6, bO7);
        STOREA(As0, a0a, a0b);
        BAR();
    }
    // ---- tail: tiles 252..255 (bE=252, bO=253, a1=253, a2=254, a3=255; As0=252) ----
    COMPUTE(As0, bE0, bE1, bE2, bE3, bE4, bE5, bE6, bE7);          // 252
    LOADB(254, bE0, bE1, bE2, bE3, bE4, bE5, bE6, bE7);
    STOREA(As1, a1a, a1b);                                         // 253
    BAR();
    COMPUTE(As1, bO0, bO1, bO2, bO3, bO4, bO5, bO6, bO7);          // 253
    LOADB(255, bO0, bO1, bO2, bO3, bO4, bO5, bO6, bO7);
    STOREA(As0, a2a, a2b);                                         // 254
    BAR();
    COMPUTE(As0, bE0, bE1, bE2, bE3, bE4, bE5, bE6, bE7);          // 254
    STOREA(As1, a3a, a3b);                                         // 255
    BAR();
    COMPUTE(As1, bO0, bO1, bO2, bO3, bO4, bO5, bO6, bO7);          // 255
    __syncthreads();   // full drain before reusing LDS as agg

    // ---- epilogue: acc -> LDS agg (f32), then per-row W[type] dots ----
    float* agg = (float*)lds;   // [64][132]
#pragma unroll
    for (int r = 0; r < 4; ++r) {
        const int gr = (mrow + (lane >> 4) * 4 + r) * 132 + ncol + (lane & 15);
        agg[gr +  0] = acc0[r];
        agg[gr + 16] = acc1[r];
        agg[gr + 32] = acc2[r];
        agg[gr + 48] = acc3[r];
    }
    __syncthreads();

    const int rbase = w * 8;   // 8 rows per wave
    for (int rr = 0; rr < 8; ++rr) {
        const int rw = rbase + rr;
        const int nn = m0 + rw;
        const int ty = types[nn];                      // wave-uniform
        const unsigned short* Wt = g_Wb + ty * (DIM * DIM);
        const int o0 = lane * 2;
        const float* aggRow = agg + rw * 132;
        float s0 = 0.f, s1 = 0.f;
#pragma unroll
        for (int d0 = 0; d0 < DIM; d0 += 8) {
            float4 ga = *(const float4*)(aggRow + d0);
            float4 gb = *(const float4*)(aggRow + d0 + 4);
            uint4 wa = *(const uint4*)(Wt + o0 * DIM + d0);
            uint4 wb = *(const uint4*)(Wt + (o0 + 1) * DIM + d0);
            s0 += ga.x * BF_LO(wa.x) + ga.y * BF_HI(wa.x) + ga.z * BF_LO(wa.y) + ga.w * BF_HI(wa.y);
            s0 += gb.x * BF_LO(wa.z) + gb.y * BF_HI(wa.z) + gb.z * BF_LO(wa.w) + gb.w * BF_HI(wa.w);
            s1 += ga.x * BF_LO(wb.x) + ga.y * BF_HI(wb.x) + ga.z * BF_LO(wb.y) + ga.w * BF_HI(wb.y);
            s1 += gb.x * BF_LO(wb.z) + gb.y * BF_HI(wb.z) + gb.z * BF_LO(wb.w) + gb.w * BF_HI(wb.w);
        }
        float2 res; res.x = s0; res.y = s1;
        *(float2*)(out + (size_t)nn * DIM + o0) = res;
    }
}

// ---------------- launch ----------------

extern "C" void kernel_launch(void* const* d_in, const int* in_sizes, int n_in,
                              void* d_out, int out_size, void* d_ws, size_t ws_size,
                              hipStream_t stream) {
    const float* x     = (const float*)d_in[0];
    const int*   types = (const int*)d_in[1];
    const float* adj   = (const float*)d_in[2];
    const float* wt    = (const float*)d_in[3];
    float* out = (float*)d_out;

    hipLaunchKernelGGL(prep_all, dim3(96), dim3(256), 0, stream, x, wt);
    hipLaunchKernelGGL(gconv_main, dim3(N_NODES / BM), dim3(512), 0, stream, adj, types, out);
}

// Round 9
// 428.476 us; speedup vs baseline: 2.0772x; 1.5922x over previous
//
#include <hip/hip_runtime.h>
#include <stdint.h>

// GraphConvLayer: out[n,:] = W[type[n]] @ (A @ x)[n,:]
// N=16384, D=128, T=8.  A is 1 GiB f32 read exactly once -> HBM floor ~163us.
// Round 9 = Round 3 (366us, the only >=3TB/s structure) + split-K=2.
// Lessons: register-resident B prefetch collapses (R6/R7/R8: VGPR 60-84);
// only load->LDS-store->barrier pipelines survive the compiler. So keep R3's
// exact tile/pipeline and fix its real problem: 1 block/CU barrier convoy.
// SPLITK=2 -> grid 512 -> 2 independent blocks/CU whose phases interleave.
// Partials to a device buffer; small epilogue reduces + applies W (f32).

#define N_NODES 16384
#define DIM     128
#define NTYPES  8
#define BM      64
#define BK      64
#define SPLITK  2
#define KSLICE  (N_NODES / SPLITK)   // 8192
#define NIT_S   (KSLICE / BK)        // 128

typedef float  f32x4  __attribute__((ext_vector_type(4)));
typedef __bf16 bf16x4 __attribute__((ext_vector_type(4)));
typedef __bf16 bf16x8 __attribute__((ext_vector_type(8)));

__device__ __attribute__((aligned(16))) unsigned short g_xT[DIM * N_NODES];    // [d][n], 4 MiB bf16
__device__ __attribute__((aligned(16))) float g_part[SPLITK * N_NODES * DIM];  // 16 MiB f32 partials

__device__ __forceinline__ unsigned int f2b(float f) {
    unsigned int u = __float_as_uint(f);
    u += 0x7FFFu + ((u >> 16) & 1u);   // round-to-nearest-even
    return u >> 16;
}

__device__ __forceinline__ bf16x4 cvt4(const float4 v) {
    bf16x4 r;
    r[0] = (__bf16)v.x; r[1] = (__bf16)v.y; r[2] = (__bf16)v.z; r[3] = (__bf16)v.w;
    return r;
}

// ---------------- prep: x -> bf16 transposed [d][n] ----------------

__global__ void prep_xT(const float* __restrict__ x) {
    int n = blockIdx.x * 256 + threadIdx.x;          // 64 blocks x 256
    const float* row = x + (size_t)n * DIM;
#pragma unroll
    for (int d0 = 0; d0 < DIM; d0 += 4) {
        float4 v = *(const float4*)(row + d0);
        g_xT[(d0 + 0) * N_NODES + n] = (unsigned short)f2b(v.x);
        g_xT[(d0 + 1) * N_NODES + n] = (unsigned short)f2b(v.y);
        g_xT[(d0 + 2) * N_NODES + n] = (unsigned short)f2b(v.z);
        g_xT[(d0 + 3) * N_NODES + n] = (unsigned short)f2b(v.w);
    }
}

// ---------------- main GEMM kernel (R3 pipeline, split-K) ----------------

#define ASTRIDE 72                           // 64 + 8 pad shorts (144 B rows)
#define ABYTES  (BM * ASTRIDE * 2)           // 9216 B per A buffer
#define XBYTES  (DIM * ASTRIDE * 2)          // 18432 B per X buffer

// barrier with LDS-visibility only: VMEM prefetch stays in flight
#define BAR() asm volatile("s_waitcnt lgkmcnt(0)\n\ts_barrier" ::: "memory")

// load tile t of A (2x float4) and X (2x uint4) into named regs
#define LOADG(t, rA0, rA1, rX0, rX1) do {                        \
    rA0 = *(const float4*)(aPtr0 + (size_t)(t) * BK);            \
    rA1 = *(const float4*)(aPtr1 + (size_t)(t) * BK);            \
    rX0 = *(const uint4*)(xPtr0 + (size_t)(t) * BK);             \
    rX1 = *(const uint4*)(xPtr1 + (size_t)(t) * BK);             \
} while (0)

// convert+store one tile's regs into LDS buffers
#define STORE(As_, Xs_, rA0, rA1, rX0, rX1) do {                 \
    *(bf16x4*)((As_) + ar0 * ASTRIDE + ak)        = cvt4(rA0);   \
    *(bf16x4*)((As_) + (ar0 + 32) * ASTRIDE + ak) = cvt4(rA1);   \
    *(uint4*)((Xs_) + xc0 * ASTRIDE + xg * 8) = rX0;             \
    *(uint4*)((Xs_) + (xc0 + 64) * ASTRIDE + xg * 8) = rX1;      \
} while (0)

#define MFMA4(As_, Xs_, kkv) do {                                                      \
    bf16x8 a_  = *(const bf16x8*)((As_) + (mrow + (lane & 15)) * ASTRIDE + (kkv));     \
    bf16x8 b0_ = *(const bf16x8*)((Xs_) + (ncol +  0 + (lane & 15)) * ASTRIDE + (kkv));\
    bf16x8 b1_ = *(const bf16x8*)((Xs_) + (ncol + 16 + (lane & 15)) * ASTRIDE + (kkv));\
    bf16x8 b2_ = *(const bf16x8*)((Xs_) + (ncol + 32 + (lane & 15)) * ASTRIDE + (kkv));\
    bf16x8 b3_ = *(const bf16x8*)((Xs_) + (ncol + 48 + (lane & 15)) * ASTRIDE + (kkv));\
    acc0 = __builtin_amdgcn_mfma_f32_16x16x32_bf16(a_, b0_, acc0, 0, 0, 0);            \
    acc1 = __builtin_amdgcn_mfma_f32_16x16x32_bf16(a_, b1_, acc1, 0, 0, 0);            \
    acc2 = __builtin_amdgcn_mfma_f32_16x16x32_bf16(a_, b2_, acc2, 0, 0, 0);            \
    acc3 = __builtin_amdgcn_mfma_f32_16x16x32_bf16(a_, b3_, acc3, 0, 0, 0);            \
} while (0)

#define COMPUTE(As_, Xs_) do {           \
    const int kkc = (lane >> 4) * 8;     \
    MFMA4(As_, Xs_, kkc);                \
    MFMA4(As_, Xs_, kkc + 32);           \
} while (0)

__global__ __launch_bounds__(512, 4) void gconv_main(const float* __restrict__ adj)
{
    __shared__ __align__(16) unsigned char lds[2 * ABYTES + 2 * XBYTES]; // 55296 B
    unsigned short* As0 = (unsigned short*)lds;
    unsigned short* As1 = As0 + BM * ASTRIDE;
    unsigned short* Xs0 = As0 + 2 * BM * ASTRIDE;
    unsigned short* Xs1 = Xs0 + DIM * ASTRIDE;

    const int tid  = threadIdx.x;
    const int w    = tid >> 6;          // 0..7
    const int lane = tid & 63;
    const int ks   = blockIdx.x & 1;               // k-slice
    const int m0   = (blockIdx.x >> 1) * BM;       // row block
    const int kb   = ks * KSLICE;

    const int mrow = (w & 3) * 16;      // wave's 16 output rows (of 64)
    const int ncol = (w >> 2) * 64;     // wave's 64 output cols (of 128)

    f32x4 acc0 = {}, acc1 = {}, acc2 = {}, acc3 = {};

    // staging index math (512 threads per tile)
    const int ar0 = tid >> 4;                 // A rows 0..31 (+32)
    const int ak  = (tid & 15) * 4;           // 4-elem chunk in row
    const int xc0 = tid >> 3;                 // X rows (d) 0..63 (+64)
    const int xg  = tid & 7;                  // 16B granule in k
    const float* aBase = adj + (size_t)m0 * N_NODES + kb;
    const float* aPtr0 = aBase + (size_t)ar0 * N_NODES + ak;
    const float* aPtr1 = aBase + (size_t)(ar0 + 32) * N_NODES + ak;
    const unsigned short* xPtr0 = g_xT + (size_t)xc0 * N_NODES + kb + xg * 8;
    const unsigned short* xPtr1 = g_xT + (size_t)(xc0 + 64) * N_NODES + kb + xg * 8;

    // 4 named register parities (NO arrays -> NO scratch, rule #20)
    float4 aP0a, aP0b, aP1a, aP1b, aP2a, aP2b, aP3a, aP3b;
    uint4  xP0a, xP0b, xP1a, xP1b, xP2a, xP2b, xP3a, xP3b;

    // ---- prologue: 4 tiles in flight, tile 0 staged ----
    LOADG(0, aP0a, aP0b, xP0a, xP0b);
    LOADG(1, aP1a, aP1b, xP1a, xP1b);
    LOADG(2, aP2a, aP2b, xP2a, xP2b);
    LOADG(3, aP3a, aP3b, xP3a, xP3b);
    STORE(As0, Xs0, aP0a, aP0b, xP0a, xP0b);
    BAR();

    // ---- steady state: 4 phases/iter; tile t's STORE is 3 phases after
    // its LOADG issued. i = 0..30 computes tiles 0..123. ----
    for (int i = 0; i < NIT_S / 4 - 1; ++i) {
        const int t0 = 4 * i;
        LOADG(t0 + 4, aP0a, aP0b, xP0a, xP0b);
        COMPUTE(As0, Xs0);
        STORE(As1, Xs1, aP1a, aP1b, xP1a, xP1b);
        BAR();
        LOADG(t0 + 5, aP1a, aP1b, xP1a, xP1b);
        COMPUTE(As1, Xs1);
        STORE(As0, Xs0, aP2a, aP2b, xP2a, xP2b);
        BAR();
        LOADG(t0 + 6, aP2a, aP2b, xP2a, xP2b);
        COMPUTE(As0, Xs0);
        STORE(As1, Xs1, aP3a, aP3b, xP3a, xP3b);
        BAR();
        LOADG(t0 + 7, aP3a, aP3b, xP3a, xP3b);
        COMPUTE(As1, Xs1);
        STORE(As0, Xs0, aP0a, aP0b, xP0a, xP0b);
        BAR();
    }
    // ---- tail: tiles 124..127, no more loads ----
    COMPUTE(As0, Xs0);
    STORE(As1, Xs1, aP1a, aP1b, xP1a, xP1b);
    BAR();
    COMPUTE(As1, Xs1);
    STORE(As0, Xs0, aP2a, aP2b, xP2a, xP2b);
    BAR();
    COMPUTE(As0, Xs0);
    STORE(As1, Xs1, aP3a, aP3b, xP3a, xP3b);
    BAR();
    COMPUTE(As1, Xs1);

    // ---- partial store: f32 accumulators to g_part[ks] ----
    float* pp = g_part + (size_t)ks * (N_NODES * DIM)
              + (size_t)(m0 + mrow + (lane >> 4) * 4) * DIM + ncol + (lane & 15);
#define STACC(nt) do {                          \
    pp[0 * DIM + (nt) * 16] = acc##nt[0];       \
    pp[1 * DIM + (nt) * 16] = acc##nt[1];       \
    pp[2 * DIM + (nt) * 16] = acc##nt[2];       \
    pp[3 * DIM + (nt) * 16] = acc##nt[3];       \
} while (0)
    STACC(0); STACC(1); STACC(2); STACC(3);
#undef STACC
}

// ---------------- epilogue: reduce partials + W[type] projection (f32) ----------------

__global__ __launch_bounds__(256) void gconv_epi(
    const float* __restrict__ wt,
    const int* __restrict__ types,
    float* __restrict__ out)
{
    __shared__ __align__(16) float agg[BM * 132];   // 33792 B

    const int tid  = threadIdx.x;
    const int w    = tid >> 6;
    const int lane = tid & 63;
    const int m0   = blockIdx.x * BM;

    // phase 1: agg[node][d] = part0 + part1
#pragma unroll
    for (int j = 0; j < 8; ++j) {
        const int f    = tid + j * 256;        // float4 index within 64x128 tile
        const int node = f >> 5;
        const int d4   = (f & 31) * 4;
        const float* p = g_part + (size_t)(m0 + node) * DIM + d4;
        float4 s0 = *(const float4*)(p);
        float4 s1 = *(const float4*)(p + (size_t)N_NODES * DIM);
        float4 s; s.x = s0.x + s1.x; s.y = s0.y + s1.y;
        s.z = s0.z + s1.z; s.w = s0.w + s1.w;
        *(float4*)&agg[node * 132 + d4] = s;
    }
    __syncthreads();

    // phase 2: out[n] = W[type[n]] @ agg[n]  (f32, lane -> 2 output features)
    const int rbase = w * 16;   // 16 nodes per wave
    for (int rr = 0; rr < 16; ++rr) {
        const int rw = rbase + rr;
        const int nn = m0 + rw;
        const int ty = types[nn];                       // wave-uniform
        const float* Wt = wt + (size_t)ty * DIM * DIM;
        const int o0 = lane * 2;
        const float* aggRow = agg + rw * 132;
        float s0 = 0.f, s1 = 0.f;
#pragma unroll
        for (int d0 = 0; d0 < DIM; d0 += 8) {
            float4 ga = *(const float4*)(aggRow + d0);
            float4 gb = *(const float4*)(aggRow + d0 + 4);
            float4 wa0 = *(const float4*)(Wt + (size_t)o0 * DIM + d0);
            float4 wa1 = *(const float4*)(Wt + (size_t)o0 * DIM + d0 + 4);
            float4 wb0 = *(const float4*)(Wt + (size_t)(o0 + 1) * DIM + d0);
            float4 wb1 = *(const float4*)(Wt + (size_t)(o0 + 1) * DIM + d0 + 4);
            s0 += ga.x * wa0.x + ga.y * wa0.y + ga.z * wa0.z + ga.w * wa0.w;
            s0 += gb.x * wa1.x + gb.y * wa1.y + gb.z * wa1.z + gb.w * wa1.w;
            s1 += ga.x * wb0.x + ga.y * wb0.y + ga.z * wb0.z + ga.w * wb0.w;
            s1 += gb.x * wb1.x + gb.y * wb1.y + gb.z * wb1.z + gb.w * wb1.w;
        }
        float2 res; res.x = s0; res.y = s1;
        *(float2*)(out + (size_t)nn * DIM + o0) = res;
    }
}

// ---------------- launch ----------------

extern "C" void kernel_launch(void* const* d_in, const int* in_sizes, int n_in,
                              void* d_out, int out_size, void* d_ws, size_t ws_size,
                              hipStream_t stream) {
    const float* x     = (const float*)d_in[0];
    const int*   types = (const int*)d_in[1];
    const float* adj   = (const float*)d_in[2];
    const float* wt    = (const float*)d_in[3];
    float* out = (float*)d_out;

    hipLaunchKernelGGL(prep_xT, dim3(64), dim3(256), 0, stream, x);
    hipLaunchKernelGGL(gconv_main, dim3((N_NODES / BM) * SPLITK), dim3(512), 0, stream, adj);
    hipLaunchKernelGGL(gconv_epi, dim3(N_NODES / BM), dim3(256), 0, stream, wt, types, out);
}

// Round 10
// 350.821 us; speedup vs baseline: 2.5370x; 1.2214x over previous
//
#include <hip/hip_runtime.h>
#include <stdint.h>

// GraphConvLayer: out[n,:] = W[type[n]] @ (A @ x)[n,:]
// N=16384, D=128, T=8.  A is 1 GiB f32 read exactly once -> HBM floor ~163us.
// Round 10: global_load_lds DMA staging + counted-vmcnt phases (T3/T4).
//  - No register staging at all: DMA has no dest register -> RA cannot
//    collapse the pipeline (R6/R7/R8 failure mode) and no ds_write phase
//    (R3/R9 LDS-copy cost).
//  - BK=32, triple-buffered A(f32)+X(bf16) tiles (48KB LDS), loads issued
//    2 phases ahead; s_waitcnt vmcnt(2) + s_barrier once per tile; vmcnt
//    never 0 in steady state -> HBM stream never drains.
//  - DMA LDS dest is linear (wave base + lane*16, m104); bank-spread via
//    pre-swizzled GLOBAL source + matching XOR on read offsets (m173/T2):
//    A: chunk ^= row&7 (8x16B chunks/row), X: chunk ^= (d>>1)&3 (4/row).

#define N_NODES 16384
#define DIM     128
#define NTYPES  8
#define BM      64
#define BK      32
#define NIT     (N_NODES / BK)   // 512

typedef float  f32x4  __attribute__((ext_vector_type(4)));
typedef __bf16 bf16x8 __attribute__((ext_vector_type(8)));

__device__ __attribute__((aligned(16))) unsigned short g_xT[DIM * N_NODES];      // [d][n], 4 MiB bf16
__device__ __attribute__((aligned(16))) unsigned short g_Wb[NTYPES * DIM * DIM]; // [t][o][d], 256 KiB

__device__ __forceinline__ unsigned int f2b(float f) {
    unsigned int u = __float_as_uint(f);
    u += 0x7FFFu + ((u >> 16) & 1u);   // round-to-nearest-even
    return u >> 16;
}
#define BF_LO(u) __uint_as_float((unsigned int)(u) << 16)
#define BF_HI(u) __uint_as_float((unsigned int)(u) & 0xFFFF0000u)

__device__ __forceinline__ bf16x8 cvt8(const f32x4 lo, const f32x4 hi) {
    bf16x8 r;
    r[0] = (__bf16)lo[0]; r[1] = (__bf16)lo[1]; r[2] = (__bf16)lo[2]; r[3] = (__bf16)lo[3];
    r[4] = (__bf16)hi[0]; r[5] = (__bf16)hi[1]; r[6] = (__bf16)hi[2]; r[7] = (__bf16)hi[3];
    return r;
}

// ---------------- fused prep kernel ----------------
// blocks 0..63: xT transpose+convert; blocks 64..95: W convert.

__global__ void prep_all(const float* __restrict__ x, const float* __restrict__ w) {
    const int tid = threadIdx.x;
    if (blockIdx.x < 64) {
        int n = blockIdx.x * 256 + tid;
        const float* row = x + (size_t)n * DIM;
#pragma unroll
        for (int d0 = 0; d0 < DIM; d0 += 4) {
            float4 v = *(const float4*)(row + d0);
            g_xT[(d0 + 0) * N_NODES + n] = (unsigned short)f2b(v.x);
            g_xT[(d0 + 1) * N_NODES + n] = (unsigned short)f2b(v.y);
            g_xT[(d0 + 2) * N_NODES + n] = (unsigned short)f2b(v.z);
            g_xT[(d0 + 3) * N_NODES + n] = (unsigned short)f2b(v.w);
        }
    } else {
        int base = ((blockIdx.x - 64) * 256 + tid) * 16;
#pragma unroll
        for (int j = 0; j < 4; ++j) {
            float4 v = *(const float4*)(w + base + j * 4);
            ushort4 o;
            o.x = (unsigned short)f2b(v.x); o.y = (unsigned short)f2b(v.y);
            o.z = (unsigned short)f2b(v.z); o.w = (unsigned short)f2b(v.w);
            *(ushort4*)(g_Wb + base + j * 4) = o;
        }
    }
}

// ---------------- main fused kernel ----------------

#define ABYTES 8192   // A tile: 64 rows x 32 f32 (128B rows, 8x16B chunks)
#define XBYTES 8192   // X tile: 128 d-rows x 32 bf16 (64B rows, 4x16B chunks)

#define GLOAD16(g, l) __builtin_amdgcn_global_load_lds(                         \
    (const __attribute__((address_space(1))) unsigned int*)(g),                 \
    (__attribute__((address_space(3))) unsigned int*)(l), 16, 0, 0)

#define COMPUTE(Ab, Xb) do {                                                    \
    f32x4 _lo = *(const f32x4*)((Ab) + aoE);                                    \
    f32x4 _hi = *(const f32x4*)((Ab) + aoO);                                    \
    bf16x8 _af = cvt8(_lo, _hi);                                                \
    bf16x8 _b0 = *(const bf16x8*)((Xb) + xbase);                                \
    bf16x8 _b1 = *(const bf16x8*)((Xb) + xbase + 1024);                         \
    bf16x8 _b2 = *(const bf16x8*)((Xb) + xbase + 2048);                         \
    bf16x8 _b3 = *(const bf16x8*)((Xb) + xbase + 3072);                         \
    acc0 = __builtin_amdgcn_mfma_f32_16x16x32_bf16(_af, _b0, acc0, 0, 0, 0);    \
    acc1 = __builtin_amdgcn_mfma_f32_16x16x32_bf16(_af, _b1, acc1, 0, 0, 0);    \
    acc2 = __builtin_amdgcn_mfma_f32_16x16x32_bf16(_af, _b2, acc2, 0, 0, 0);    \
    acc3 = __builtin_amdgcn_mfma_f32_16x16x32_bf16(_af, _b3, acc3, 0, 0, 0);    \
} while (0)

// phase: counted vmcnt (t's 2 DMAs done; t+1's stay in flight) -> barrier ->
// issue t+2 -> compute t.  Barrier-first makes the t+2 overwrite safe.
#define PHASE_I(Ac, Xc, Ai, Xi, VM) do {                                        \
    asm volatile("s_waitcnt vmcnt(" VM ")" ::: "memory");                       \
    __builtin_amdgcn_s_barrier();                                               \
    GLOAD16(gAp, (Ai) + wq);                                                    \
    GLOAD16(gXp, (Xi) + wq);                                                    \
    gAp += BK; gXp += BK;                                                       \
    COMPUTE(Ac, Xc);                                                            \
} while (0)

#define PHASE_N(Ac, Xc, VM) do {                                                \
    asm volatile("s_waitcnt vmcnt(" VM ")" ::: "memory");                       \
    __builtin_amdgcn_s_barrier();                                               \
    COMPUTE(Ac, Xc);                                                            \
} while (0)

__global__ __launch_bounds__(512, 1) void gconv_main(
    const float* __restrict__ adj,
    const int* __restrict__ types,
    float* __restrict__ out)
{
    __shared__ __align__(16) unsigned char lds[3 * ABYTES + 3 * XBYTES]; // 49152 B
    unsigned char* A0 = lds;
    unsigned char* A1 = lds + ABYTES;
    unsigned char* A2 = lds + 2 * ABYTES;
    unsigned char* X0 = lds + 3 * ABYTES;
    unsigned char* X1 = X0 + XBYTES;
    unsigned char* X2 = X0 + 2 * XBYTES;

    const int tid  = threadIdx.x;
    const int w    = tid >> 6;          // 0..7
    const int l    = tid & 63;
    const int m0   = blockIdx.x * BM;

    const int mrow = (w & 3) * 16;      // wave's 16 output rows (of 64)
    const int ncol = (w >> 2) * 64;     // wave's 64 output cols (of 128)

    f32x4 acc0 = {}, acc1 = {}, acc2 = {}, acc3 = {};

    // ---- DMA per-lane source pointers (pre-swizzled, m173) ----
    // A call (1KB = 8 rows x 128B): row = 8w+(l>>3), src chunk = (l&7)^(l>>3)
    const float* gAp = adj + (size_t)(m0 + 8 * w + (l >> 3)) * N_NODES
                     + (((l & 7) ^ (l >> 3)) << 2);
    // X call (1KB = 16 d-rows x 64B): d = 16w+(l>>2), src chunk = (l&3)^((l>>3)&3)
    const unsigned short* gXp = g_xT + (size_t)(16 * w + (l >> 2)) * N_NODES
                              + (((l & 3) ^ ((l >> 3) & 3)) << 3);
    const int wq = w << 10;             // this wave's 1KB slot in each buffer

    // ---- compute-side per-lane byte offsets (XOR matches DMA swizzle) ----
    const int arow = mrow + (l & 15);
    const int ce   = (l >> 4) << 1;                       // logical A chunk (even)
    const int aoE  = arow * 128 + ((ce ^ (l & 7)) << 4);
    const int aoO  = arow * 128 + (((ce + 1) ^ (l & 7)) << 4);
    const int xph  = (l >> 4) ^ (((l & 15) >> 1) & 3);    // physical X chunk
    const int xbase = (ncol + (l & 15)) * 64 + (xph << 4);  // + nt*1024 per frag

    // ---- prologue: tiles 0 and 1 in flight (4 DMAs/wave outstanding) ----
    GLOAD16(gAp, A0 + wq); GLOAD16(gXp, X0 + wq); gAp += BK; gXp += BK;
    GLOAD16(gAp, A1 + wq); GLOAD16(gXp, X1 + wq); gAp += BK; gXp += BK;

    // ---- 512 phases: 169 x 3 steady + 5 tail ----
    for (int j = 0; j < 169; ++j) {
        PHASE_I(A0, X0, A2, X2, "2");   // t=3j   : compute buf0, issue t+2 -> buf2
        PHASE_I(A1, X1, A0, X0, "2");   // t=3j+1 : compute buf1, issue -> buf0
        PHASE_I(A2, X2, A1, X1, "2");   // t=3j+2 : compute buf2, issue -> buf1
    }
    PHASE_I(A0, X0, A2, X2, "2");       // t=507, issue 509 -> buf2
    PHASE_I(A1, X1, A0, X0, "2");       // t=508, issue 510 -> buf0
    PHASE_I(A2, X2, A1, X1, "2");       // t=509, issue 511 -> buf1
    PHASE_N(A0, X0, "2");               // t=510
    PHASE_N(A1, X1, "0");               // t=511
    __syncthreads();                    // full drain before reusing LDS as agg

    // ---- epilogue: acc -> LDS agg (f32), then per-row W[type] dots ----
    float* agg = (float*)lds;   // [64][132] = 33792 B
#pragma unroll
    for (int r = 0; r < 4; ++r) {
        const int gr = (mrow + (l >> 4) * 4 + r) * 132 + ncol + (l & 15);
        agg[gr +  0] = acc0[r];
        agg[gr + 16] = acc1[r];
        agg[gr + 32] = acc2[r];
        agg[gr + 48] = acc3[r];
    }
    __syncthreads();

    const int rbase = w * 8;   // 8 rows per wave
    for (int rr = 0; rr < 8; ++rr) {
        const int rw = rbase + rr;
        const int nn = m0 + rw;
        const int ty = types[nn];                      // wave-uniform
        const unsigned short* Wt = g_Wb + ty * (DIM * DIM);
        const int o0 = l * 2;
        const float* aggRow = agg + rw * 132;
        float s0 = 0.f, s1 = 0.f;
#pragma unroll
        for (int d0 = 0; d0 < DIM; d0 += 8) {
            float4 ga = *(const float4*)(aggRow + d0);
            float4 gb = *(const float4*)(aggRow + d0 + 4);
            uint4 wa = *(const uint4*)(Wt + o0 * DIM + d0);
            uint4 wb = *(const uint4*)(Wt + (o0 + 1) * DIM + d0);
            s0 += ga.x * BF_LO(wa.x) + ga.y * BF_HI(wa.x) + ga.z * BF_LO(wa.y) + ga.w * BF_HI(wa.y);
            s0 += gb.x * BF_LO(wa.z) + gb.y * BF_HI(wa.z) + gb.z * BF_LO(wa.w) + gb.w * BF_HI(wa.w);
            s1 += ga.x * BF_LO(wb.x) + ga.y * BF_HI(wb.x) + ga.z * BF_LO(wb.y) + ga.w * BF_HI(wb.y);
            s1 += gb.x * BF_LO(wb.z) + gb.y * BF_HI(wb.z) + gb.z * BF_LO(wb.w) + gb.w * BF_HI(wb.w);
        }
        float2 res; res.x = s0; res.y = s1;
        *(float2*)(out + (size_t)nn * DIM + o0) = res;
    }
}

// ---------------- launch ----------------

extern "C" void kernel_launch(void* const* d_in, const int* in_sizes, int n_in,
                              void* d_out, int out_size, void* d_ws, size_t ws_size,
                              hipStream_t stream) {
    const float* x     = (const float*)d_in[0];
    const int*   types = (const int*)d_in[1];
    const float* adj   = (const float*)d_in[2];
    const float* wt    = (const float*)d_in[3];
    float* out = (float*)d_out;

    hipLaunchKernelGGL(prep_all, dim3(96), dim3(256), 0, stream, x, wt);
    hipLaunchKernelGGL(gconv_main, dim3(N_NODES / BM), dim3(512), 0, stream, adj, types, out);
}